// Round 1
// baseline (1002.158 us; speedup 1.0000x reference)
//
#include <hip/hip_runtime.h>
#include <hip/hip_bf16.h>

#define Hh 56
#define Ww 56
#define Cc 256
#define Tt 16
#define Bb 4
#define Nn 3136
#define Kk 784
#define KX 28
#define Dd 128
#define Mc 64
#define NTOP 32

// ---------------- K1: affine warp + bilinear sample + row pool ----------------
// grid: T*B*H blocks, 256 thr. rp layout: [(t*B+b)*H + h][c*28+kx]
__global__ __launch_bounds__(256) void k_warp_rowpool(
    const float* __restrict__ fm, const float* __restrict__ Abank, float* __restrict__ rp) {
  int blk = blockIdx.x;
  int t = blk / (Bb * Hh);
  int rem = blk % (Bb * Hh);
  int b = rem / Hh;
  int h = rem % Hh;
  __shared__ float wsm[Cc * Ww];
  __shared__ int sx0[Ww], sx1[Ww], sy0[Ww], sy1[Ww];
  __shared__ float swx[Ww], swy[Ww];
  const float* A = Abank + t * 6;
  float a00 = A[0], a01 = A[1], a02 = A[2], a10 = A[3], a11 = A[4], a12 = A[5];
  float gy = (2.0f * h + 1.0f) / 56.0f - 1.0f;
  int tid = threadIdx.x;
  if (tid < Ww) {
    float gx = (2.0f * tid + 1.0f) / 56.0f - 1.0f;
    float u = a00 * gx + a01 * gy + a02;
    float v = a10 * gx + a11 * gy + a12;
    float ix = ((u + 1.0f) * 56.0f - 1.0f) * 0.5f;
    float iy = ((v + 1.0f) * 56.0f - 1.0f) * 0.5f;
    float x0f = floorf(ix), y0f = floorf(iy);
    int x0 = (int)x0f, y0 = (int)y0f;
    swx[tid] = ix - x0f;
    swy[tid] = iy - y0f;
    sx0[tid] = min(max(x0, 0), 55);
    sx1[tid] = min(max(x0 + 1, 0), 55);
    sy0[tid] = min(max(y0, 0), 55);
    sy1[tid] = min(max(y0 + 1, 0), 55);
  }
  __syncthreads();
  const float* fb = fm + (size_t)b * Cc * Hh * Ww;
  for (int e = tid; e < Cc * Ww; e += 256) {
    int c = e / Ww;
    int x = e - c * Ww;
    const float* f = fb + (size_t)c * (Hh * Ww);
    int x0 = sx0[x], x1 = sx1[x], y0 = sy0[x], y1 = sy1[x];
    float wx = swx[x], wy = swy[x];
    float v00 = f[y0 * Ww + x0], v01 = f[y0 * Ww + x1];
    float v10 = f[y1 * Ww + x0], v11 = f[y1 * Ww + x1];
    float top = v00 + wx * (v01 - v00);
    float bot = v10 + wx * (v11 - v10);
    wsm[e] = top + wy * (bot - top);
  }
  __syncthreads();
  float* out = rp + (size_t)blk * (Cc * KX);
  for (int e = tid; e < Cc * KX; e += 256) {
    int c = e / KX;
    int kx = e - c * KX;
    int xs = 2 * kx - 4;
    int lo = max(xs, 0), hi = min(xs + 8, 55);
    float s = 0.f;
    for (int x = lo; x <= hi; ++x) s += wsm[c * Ww + x];
    out[e] = s;
  }
}

// ---------------- K2: column pool -> pm [(t*B+b)*C + c][ky*28+kx], /81 -------
__global__ __launch_bounds__(256) void k_colpool(
    const float* __restrict__ rp, float* __restrict__ pm) {
  int blk = blockIdx.x;      // tb*28 + ky
  int tb = blk / KX;
  int ky = blk % KX;
  int hs = 2 * ky - 4;
  int lo = max(hs, 0), hi = min(hs + 8, 55);
  const float* base = rp + (size_t)tb * (Hh * Cc * KX);
  for (int e = threadIdx.x; e < Cc * KX; e += 256) {
    float s = 0.f;
    for (int h = lo; h <= hi; ++h) s += base[(size_t)h * (Cc * KX) + e];
    int c = e / KX, kx = e - c * KX;
    pm[((size_t)tb * Cc + c) * Kk + ky * KX + kx] = s * (1.0f / 81.0f);
  }
}

// ---------------- K3a: combined weight Wc^T [c][d] and bias bc ---------------
__global__ __launch_bounds__(128) void k_wc(
    const float* __restrict__ pw_w, const float* __restrict__ pw_b,
    const float* __restrict__ proj_w, const float* __restrict__ proj_b,
    float* __restrict__ wct, float* __restrict__ bc) {
  int c = blockIdx.x;
  int d = threadIdx.x;
  float acc = 0.f;
  for (int m = 0; m < Mc; ++m) acc += proj_w[d * Mc + m] * pw_w[m * Cc + c];
  wct[c * Dd + d] = acc;
  if (c == 0) {
    float bb = proj_b[d];
    for (int m = 0; m < Mc; ++m) bb += proj_w[d * Mc + m] * pw_b[m];
    bc[d] = bb;
  }
}

// ---------------- K3b: z[tb,k,d] = sum_c pm[tb,c,k]*wct[c,d] + bc[d] ---------
__global__ __launch_bounds__(256) void k_zgemm(
    const float* __restrict__ pm, const float* __restrict__ wct,
    const float* __restrict__ bc, float* __restrict__ z) {
  int blk = blockIdx.x;            // tb*28 + ktile
  int tb = blk / 28;
  int k0 = (blk % 28) * 28;
  int tid = threadIdx.x;
  int d = tid & 127;
  int kg = tid >> 7;               // 0..1
  __shared__ float pm_s[64 * 28];
  __shared__ float wc_s[64 * Dd];
  float acc[14];
#pragma unroll
  for (int j = 0; j < 14; ++j) acc[j] = 0.f;
  float bcd = bc[d];
  const float* pmb = pm + (size_t)tb * Cc * Kk;
  for (int c0 = 0; c0 < Cc; c0 += 64) {
    for (int idx = tid; idx < 64 * 28; idx += 256) {
      int c = idx / 28, kx = idx - c * 28;
      pm_s[idx] = pmb[(size_t)(c0 + c) * Kk + k0 + kx];
    }
    for (int idx = tid; idx < 64 * Dd; idx += 256) wc_s[idx] = wct[c0 * Dd + idx];
    __syncthreads();
    for (int c = 0; c < 64; ++c) {
      float w = wc_s[c * Dd + d];
#pragma unroll
      for (int j = 0; j < 14; ++j) acc[j] += pm_s[c * 28 + kg * 14 + j] * w;
    }
    __syncthreads();
  }
#pragma unroll
  for (int j = 0; j < 14; ++j) {
    int k = k0 + kg * 14 + j;
    z[((size_t)tb * Kk + k) * Dd + d] = acc[j] + bcd;
  }
}

// ---------------- K4: normalize z rows, s = zn . r ---------------------------
__global__ __launch_bounds__(256) void k_znorm(
    float* __restrict__ z, const float* __restrict__ r, float* __restrict__ s_arr) {
  int row = blockIdx.x * 4 + (threadIdx.x >> 6);
  int lane = threadIdx.x & 63;
  float* zr = z + (size_t)row * Dd;
  float z0 = zr[lane], z1 = zr[lane + 64];
  float ss = z0 * z0 + z1 * z1;
  for (int off = 32; off; off >>= 1) ss += __shfl_xor(ss, off);
  float inv = 1.0f / fmaxf(sqrtf(ss), 1e-6f);
  z0 *= inv; z1 *= inv;
  zr[lane] = z0; zr[lane + 64] = z1;
  float sd = z0 * r[lane] + z1 * r[lane + 64];
  for (int off = 32; off; off >>= 1) sd += __shfl_xor(sd, off);
  if (lane == 0) s_arr[row] = sd;
}

// ---------------- K5: softmax over T, g_emb ----------------------------------
__global__ __launch_bounds__(128) void k_gemb(
    const float* __restrict__ z, const float* __restrict__ s_arr, float* __restrict__ g) {
  int blk = blockIdx.x;            // b*784 + k
  int b = blk / Kk, k = blk % Kk;
  int d = threadIdx.x;
  float sv[Tt];
  float mx = -3.4e38f;
#pragma unroll
  for (int t = 0; t < Tt; ++t) {
    sv[t] = s_arr[(t * Bb + b) * Kk + k];
    mx = fmaxf(mx, sv[t]);
  }
  float sum = 0.f;
#pragma unroll
  for (int t = 0; t < Tt; ++t) {
    sv[t] = expf(10.0f * (sv[t] - mx));
    sum += sv[t];
  }
  float isum = 1.0f / sum;
  float acc = 0.f;
#pragma unroll
  for (int t = 0; t < Tt; ++t)
    acc += sv[t] * isum * z[((size_t)(t * Bb + b) * Kk + k) * Dd + d];
  g[((size_t)b * Kk + k) * Dd + d] = acc;
}

// ---------------- K6: E = normalize(M @ g) via sparse bilinear structure -----
__global__ __launch_bounds__(64) void k_E(
    const float* __restrict__ Mmat, const float* __restrict__ g, float* __restrict__ E) {
  int row = blockIdx.x;            // b*N + n
  int b = row / Nn, n = row % Nn;
  int y = n / Ww, x = n % Ww;
  int x0 = x >> 1, y0 = y >> 1;
  int x1 = min(x0 + 1, 27), y1 = min(y0 + 1, 27);
  bool hx = (x1 != x0), hy = (y1 != y0);
  int k00 = y0 * 28 + x0, k01 = y0 * 28 + x1, k10 = y1 * 28 + x0, k11 = y1 * 28 + x1;
  const float* Mr = Mmat + (size_t)n * Kk;
  float m00 = Mr[k00];
  float m01 = hx ? Mr[k01] : 0.f;
  float m10 = hy ? Mr[k10] : 0.f;
  float m11 = (hx && hy) ? Mr[k11] : 0.f;
  const float* gb = g + (size_t)b * Kk * Dd;
  int lane = threadIdx.x;
  int l2 = lane + 64;
  float a0 = m00 * gb[k00 * Dd + lane] + m01 * gb[k01 * Dd + lane] +
             m10 * gb[k10 * Dd + lane] + m11 * gb[k11 * Dd + lane];
  float a1 = m00 * gb[k00 * Dd + l2] + m01 * gb[k01 * Dd + l2] +
             m10 * gb[k10 * Dd + l2] + m11 * gb[k11 * Dd + l2];
  float ss = a0 * a0 + a1 * a1;
  for (int off = 32; off; off >>= 1) ss += __shfl_xor(ss, off);
  float inv = 1.0f / fmaxf(sqrtf(ss), 1e-6f);
  E[(size_t)row * Dd + lane] = a0 * inv;
  E[(size_t)row * Dd + l2] = a1 * inv;
}

// ---------------- K7: Saff = (E E^T) * G, tiled 64x64 ------------------------
__global__ __launch_bounds__(256) void k_saff(
    const float* __restrict__ E, const float* __restrict__ P, float* __restrict__ S) {
  int blk = blockIdx.x;
  int b = blk / (49 * 49);
  int rem = blk % (49 * 49);
  int i0 = (rem / 49) * 64, j0 = (rem % 49) * 64;
  __shared__ __align__(16) float Ei_s[64 * 68];
  __shared__ __align__(16) float Ej_s[64 * 68];
  __shared__ float s_pxi[64], s_pyi[64], s_pxj[64], s_pyj[64];
  int tid = threadIdx.x;
  const float* Eb = E + (size_t)b * Nn * Dd;
  if (tid < 64) {
    s_pxi[tid] = P[(i0 + tid) * 2];
    s_pyi[tid] = P[(i0 + tid) * 2 + 1];
    s_pxj[tid] = P[(j0 + tid) * 2];
    s_pyj[tid] = P[(j0 + tid) * 2 + 1];
  }
  int ti = tid >> 4, tj = tid & 15;
  int ib = ti * 4, jb = tj * 4;
  float acc[4][4];
#pragma unroll
  for (int a = 0; a < 4; ++a)
#pragma unroll
    for (int c = 0; c < 4; ++c) acc[a][c] = 0.f;
  for (int kc = 0; kc < Dd; kc += 64) {
    __syncthreads();
    for (int idx = tid; idx < 64 * 64; idx += 256) {
      int ii = idx >> 6, dd = idx & 63;
      Ei_s[dd * 68 + ii] = Eb[(size_t)(i0 + ii) * Dd + kc + dd];
      Ej_s[dd * 68 + ii] = Eb[(size_t)(j0 + ii) * Dd + kc + dd];
    }
    __syncthreads();
#pragma unroll 8
    for (int kk = 0; kk < 64; ++kk) {
      const float4 a = *reinterpret_cast<const float4*>(&Ei_s[kk * 68 + ib]);
      const float4 q = *reinterpret_cast<const float4*>(&Ej_s[kk * 68 + jb]);
      acc[0][0] += a.x * q.x; acc[0][1] += a.x * q.y; acc[0][2] += a.x * q.z; acc[0][3] += a.x * q.w;
      acc[1][0] += a.y * q.x; acc[1][1] += a.y * q.y; acc[1][2] += a.y * q.z; acc[1][3] += a.y * q.w;
      acc[2][0] += a.z * q.x; acc[2][1] += a.z * q.y; acc[2][2] += a.z * q.z; acc[2][3] += a.z * q.w;
      acc[3][0] += a.w * q.x; acc[3][1] += a.w * q.y; acc[3][2] += a.w * q.z; acc[3][3] += a.w * q.w;
    }
  }
  size_t ob = (size_t)b * Nn * Nn;
#pragma unroll
  for (int di = 0; di < 4; ++di) {
    int i = i0 + ib + di;
    float px = s_pxi[ib + di], py = s_pyi[ib + di];
    float vals[4];
#pragma unroll
    for (int dj = 0; dj < 4; ++dj) {
      float dx = px - s_pxj[jb + dj];
      float dy = py - s_pyj[jb + dj];
      float gg = 1.0f - expf(-(dx * dx + dy * dy) * (1.0f / 18.0f));
      vals[dj] = acc[di][dj] * gg;
    }
    float4 o = {vals[0], vals[1], vals[2], vals[3]};
    *reinterpret_cast<float4*>(&S[ob + (size_t)i * Nn + j0 + jb]) = o;
  }
}

// ---------------- K8: top-32 per row + row denom + col denom atomics ---------
__global__ __launch_bounds__(64) void k_topk(
    const float* __restrict__ S, float* __restrict__ topv, int* __restrict__ topi,
    float* __restrict__ dr, float* __restrict__ dc) {
  int row = blockIdx.x;            // b*N + i
  int b = row / Nn;
  int lane = threadIdx.x;
  const float* Sr = S + (size_t)row * Nn;
  float v[49];
#pragma unroll
  for (int j = 0; j < 49; ++j) v[j] = Sr[lane + 64 * j];
  float myv = 0.f;
  int myc = 0;
#pragma unroll 1
  for (int it = 0; it < NTOP; ++it) {
    float lm = -3.4e38f;
    int lc = 0;
#pragma unroll
    for (int j = 0; j < 49; ++j) {
      if (v[j] > lm) { lm = v[j]; lc = j; }
    }
    int col = lc * 64 + lane;
    for (int off = 32; off; off >>= 1) {
      float ov = __shfl_xor(lm, off);
      int oc = __shfl_xor(col, off);
      if (ov > lm || (ov == lm && oc < col)) { lm = ov; col = oc; }
    }
    int jc = col >> 6;
    bool own = (lane == (col & 63));
#pragma unroll
    for (int j = 0; j < 49; ++j)
      if (own && j == jc) v[j] = -3.4e38f;
    if (lane == it) { myv = lm; myc = col; }
  }
  float e = 0.f;
  if (lane < NTOP) {
    e = expf(10.0f * myv);
    topv[(size_t)row * NTOP + lane] = myv;
    topi[(size_t)row * NTOP + lane] = myc;
    atomicAdd(&dc[b * Nn + myc], e - 1.0f);
  }
  float sum = e;
  for (int off = 32; off; off >>= 1) sum += __shfl_xor(sum, off);
  if (lane == 0) dr[row] = (float)(Nn - NTOP) + sum;
}

__global__ void k_dcinit(float* __restrict__ dc) {
  int i = blockIdx.x * 256 + threadIdx.x;
  if (i < Bb * Nn) dc[i] = (float)Nn;
}

__global__ void k_inv(float* __restrict__ dr, float* __restrict__ dc) {
  int i = blockIdx.x * 256 + threadIdx.x;
  if (i < Bb * Nn) {
    dr[i] = 1.0f / dr[i];
    dc[i] = 1.0f / dc[i];
  }
}

// ---------------- K10: A0 base = invdr_i * invdc_j ---------------------------
__global__ __launch_bounds__(256) void k_base(
    const float* __restrict__ invdr, const float* __restrict__ invdc, float* __restrict__ A0) {
  int row = blockIdx.x;            // b*N + i
  int b = row / Nn;
  float idr = invdr[row];
  const float4* dc4 = reinterpret_cast<const float4*>(invdc + b * Nn);
  float4* out4 = reinterpret_cast<float4*>(A0 + (size_t)row * Nn);
  for (int j = threadIdx.x; j < Nn / 4; j += 256) {
    float4 c = dc4[j];
    float4 o = {idr * c.x, idr * c.y, idr * c.z, idr * c.w};
    out4[j] = o;
  }
}

// ---------------- K11: scatter the 32 selected entries per row ---------------
__global__ void k_fix(
    const float* __restrict__ topv, const int* __restrict__ topi,
    const float* __restrict__ invdr, const float* __restrict__ invdc, float* __restrict__ A0) {
  int gidx = blockIdx.x * 256 + threadIdx.x;
  if (gidx >= Bb * Nn * NTOP) return;
  int row = gidx >> 5;
  int b = row / Nn;
  int col = topi[gidx];
  float e = expf(10.0f * topv[gidx]);
  A0[(size_t)row * Nn + col] = e * e * invdr[row] * invdc[b * Nn + col];
}

extern "C" void kernel_launch(void* const* d_in, const int* in_sizes, int n_in,
                              void* d_out, int out_size, void* d_ws, size_t ws_size,
                              hipStream_t stream) {
  const float* fm     = (const float*)d_in[0];
  const float* Abank  = (const float*)d_in[1];
  const float* pw_w   = (const float*)d_in[2];
  const float* pw_b   = (const float*)d_in[3];
  const float* proj_w = (const float*)d_in[4];
  const float* proj_b = (const float*)d_in[5];
  const float* r      = (const float*)d_in[6];
  const float* Mmat   = (const float*)d_in[7];
  const float* P      = (const float*)d_in[8];
  float* out = (float*)d_out;
  float* E  = out;
  float* A0 = out + (size_t)Bb * Nn * Dd;

  float* ws = (float*)d_ws;
  // rp lives [K1..K2]; z written in K3b after rp is dead -> shares offset 0.
  float* rp    = ws;                       // 25,690,112 floats
  float* z     = ws;                       //  6,422,528 floats (within rp region)
  float* pm    = ws + 25690112;            // 12,845,056
  float* wct   = ws + 38535168;            //     32,768
  float* bcv   = ws + 38567936;            //        128
  float* s_arr = ws + 38568064;            //     50,176
  float* g     = ws + 38618240;            //    401,408
  float* topv  = ws + 39019648;            //    401,408
  int*   topi  = (int*)(ws + 39421056);    //    401,408
  float* dr    = ws + 39822464;            //     12,544
  float* dc    = ws + 39835008;            //     12,544

  hipLaunchKernelGGL(k_warp_rowpool, dim3(Tt * Bb * Hh), dim3(256), 0, stream, fm, Abank, rp);
  hipLaunchKernelGGL(k_colpool, dim3(Tt * Bb * KX), dim3(256), 0, stream, rp, pm);
  hipLaunchKernelGGL(k_wc, dim3(Cc), dim3(128), 0, stream, pw_w, pw_b, proj_w, proj_b, wct, bcv);
  hipLaunchKernelGGL(k_zgemm, dim3(Tt * Bb * 28), dim3(256), 0, stream, pm, wct, bcv, z);
  hipLaunchKernelGGL(k_znorm, dim3(Tt * Bb * Kk / 4), dim3(256), 0, stream, z, r, s_arr);
  hipLaunchKernelGGL(k_gemb, dim3(Bb * Kk), dim3(128), 0, stream, z, s_arr, g);
  hipLaunchKernelGGL(k_E, dim3(Bb * Nn), dim3(64), 0, stream, Mmat, g, E);
  hipLaunchKernelGGL(k_saff, dim3(Bb * 49 * 49), dim3(256), 0, stream, E, P, A0);
  hipLaunchKernelGGL(k_dcinit, dim3(49), dim3(256), 0, stream, dc);
  hipLaunchKernelGGL(k_topk, dim3(Bb * Nn), dim3(64), 0, stream, A0, topv, topi, dr, dc);
  hipLaunchKernelGGL(k_inv, dim3(49), dim3(256), 0, stream, dr, dc);
  hipLaunchKernelGGL(k_base, dim3(Bb * Nn), dim3(256), 0, stream, dr, dc, A0);
  hipLaunchKernelGGL(k_fix, dim3(Bb * Nn * NTOP / 256), dim3(256), 0, stream, topv, topi, dr, dc, A0);
}

// Round 2
// 823.191 us; speedup vs baseline: 1.2174x; 1.2174x over previous
//
#include <hip/hip_runtime.h>
#include <hip/hip_bf16.h>

#define Hh 56
#define Ww 56
#define Cc 256
#define Tt 16
#define Bb 4
#define Nn 3136
#define Kk 784
#define KX 28
#define Dd 128
#define Mc 64
#define NTOP 32

// ---------------- K1: affine warp + bilinear sample + row pool ----------------
__global__ __launch_bounds__(256) void k_warp_rowpool(
    const float* __restrict__ fm, const float* __restrict__ Abank, float* __restrict__ rp) {
  int blk = blockIdx.x;
  int t = blk / (Bb * Hh);
  int rem = blk % (Bb * Hh);
  int b = rem / Hh;
  int h = rem % Hh;
  __shared__ float wsm[Cc * Ww];
  __shared__ int sx0[Ww], sx1[Ww], sy0[Ww], sy1[Ww];
  __shared__ float swx[Ww], swy[Ww];
  const float* A = Abank + t * 6;
  float a00 = A[0], a01 = A[1], a02 = A[2], a10 = A[3], a11 = A[4], a12 = A[5];
  float gy = (2.0f * h + 1.0f) / 56.0f - 1.0f;
  int tid = threadIdx.x;
  if (tid < Ww) {
    float gx = (2.0f * tid + 1.0f) / 56.0f - 1.0f;
    float u = a00 * gx + a01 * gy + a02;
    float v = a10 * gx + a11 * gy + a12;
    float ix = ((u + 1.0f) * 56.0f - 1.0f) * 0.5f;
    float iy = ((v + 1.0f) * 56.0f - 1.0f) * 0.5f;
    float x0f = floorf(ix), y0f = floorf(iy);
    int x0 = (int)x0f, y0 = (int)y0f;
    swx[tid] = ix - x0f;
    swy[tid] = iy - y0f;
    sx0[tid] = min(max(x0, 0), 55);
    sx1[tid] = min(max(x0 + 1, 0), 55);
    sy0[tid] = min(max(y0, 0), 55);
    sy1[tid] = min(max(y0 + 1, 0), 55);
  }
  __syncthreads();
  const float* fb = fm + (size_t)b * Cc * Hh * Ww;
  for (int e = tid; e < Cc * Ww; e += 256) {
    int c = e / Ww;
    int x = e - c * Ww;
    const float* f = fb + (size_t)c * (Hh * Ww);
    int x0 = sx0[x], x1 = sx1[x], y0 = sy0[x], y1 = sy1[x];
    float wx = swx[x], wy = swy[x];
    float v00 = f[y0 * Ww + x0], v01 = f[y0 * Ww + x1];
    float v10 = f[y1 * Ww + x0], v11 = f[y1 * Ww + x1];
    float top = v00 + wx * (v01 - v00);
    float bot = v10 + wx * (v11 - v10);
    wsm[e] = top + wy * (bot - top);
  }
  __syncthreads();
  float* out = rp + (size_t)blk * (Cc * KX);
  for (int e = tid; e < Cc * KX; e += 256) {
    int c = e / KX;
    int kx = e - c * KX;
    int xs = 2 * kx - 4;
    int lo = max(xs, 0), hi = min(xs + 8, 55);
    float s = 0.f;
    for (int x = lo; x <= hi; ++x) s += wsm[c * Ww + x];
    out[e] = s;
  }
}

// ---------------- K2: column pool -> pm -------------------------------------
__global__ __launch_bounds__(256) void k_colpool(
    const float* __restrict__ rp, float* __restrict__ pm) {
  int blk = blockIdx.x;      // tb*28 + ky
  int tb = blk / KX;
  int ky = blk % KX;
  int hs = 2 * ky - 4;
  int lo = max(hs, 0), hi = min(hs + 8, 55);
  const float* base = rp + (size_t)tb * (Hh * Cc * KX);
  for (int e = threadIdx.x; e < Cc * KX; e += 256) {
    float s = 0.f;
    for (int h = lo; h <= hi; ++h) s += base[(size_t)h * (Cc * KX) + e];
    int c = e / KX, kx = e - c * KX;
    pm[((size_t)tb * Cc + c) * Kk + ky * KX + kx] = s * (1.0f / 81.0f);
  }
}

// ---------------- K3a: combined weight Wc^T [c][d] and bias bc ---------------
__global__ __launch_bounds__(128) void k_wc(
    const float* __restrict__ pw_w, const float* __restrict__ pw_b,
    const float* __restrict__ proj_w, const float* __restrict__ proj_b,
    float* __restrict__ wct, float* __restrict__ bc) {
  int c = blockIdx.x;
  int d = threadIdx.x;
  float acc = 0.f;
  for (int m = 0; m < Mc; ++m) acc += proj_w[d * Mc + m] * pw_w[m * Cc + c];
  wct[c * Dd + d] = acc;
  if (c == 0) {
    float bb = proj_b[d];
    for (int m = 0; m < Mc; ++m) bb += proj_w[d * Mc + m] * pw_b[m];
    bc[d] = bb;
  }
}

// ---------------- K3b: z[tb,k,d] = sum_c pm[tb,c,k]*wct[c,d] + bc[d] ---------
__global__ __launch_bounds__(256) void k_zgemm(
    const float* __restrict__ pm, const float* __restrict__ wct,
    const float* __restrict__ bc, float* __restrict__ z) {
  int blk = blockIdx.x;            // tb*28 + ktile
  int tb = blk / 28;
  int k0 = (blk % 28) * 28;
  int tid = threadIdx.x;
  int d = tid & 127;
  int kg = tid >> 7;               // 0..1
  __shared__ float pm_s[64 * 28];
  __shared__ float wc_s[64 * Dd];
  float acc[14];
#pragma unroll
  for (int j = 0; j < 14; ++j) acc[j] = 0.f;
  float bcd = bc[d];
  const float* pmb = pm + (size_t)tb * Cc * Kk;
  for (int c0 = 0; c0 < Cc; c0 += 64) {
    for (int idx = tid; idx < 64 * 28; idx += 256) {
      int c = idx / 28, kx = idx - c * 28;
      pm_s[idx] = pmb[(size_t)(c0 + c) * Kk + k0 + kx];
    }
    for (int idx = tid; idx < 64 * Dd; idx += 256) wc_s[idx] = wct[c0 * Dd + idx];
    __syncthreads();
    for (int c = 0; c < 64; ++c) {
      float w = wc_s[c * Dd + d];
#pragma unroll
      for (int j = 0; j < 14; ++j) acc[j] += pm_s[c * 28 + kg * 14 + j] * w;
    }
    __syncthreads();
  }
#pragma unroll
  for (int j = 0; j < 14; ++j) {
    int k = k0 + kg * 14 + j;
    z[((size_t)tb * Kk + k) * Dd + d] = acc[j] + bcd;
  }
}

// ---------------- K4: normalize z rows, s = zn . r ---------------------------
__global__ __launch_bounds__(256) void k_znorm(
    float* __restrict__ z, const float* __restrict__ r, float* __restrict__ s_arr) {
  int row = blockIdx.x * 4 + (threadIdx.x >> 6);
  int lane = threadIdx.x & 63;
  float* zr = z + (size_t)row * Dd;
  float z0 = zr[lane], z1 = zr[lane + 64];
  float ss = z0 * z0 + z1 * z1;
  for (int off = 32; off; off >>= 1) ss += __shfl_xor(ss, off);
  float inv = 1.0f / fmaxf(sqrtf(ss), 1e-6f);
  z0 *= inv; z1 *= inv;
  zr[lane] = z0; zr[lane + 64] = z1;
  float sd = z0 * r[lane] + z1 * r[lane + 64];
  for (int off = 32; off; off >>= 1) sd += __shfl_xor(sd, off);
  if (lane == 0) s_arr[row] = sd;
}

// ---------------- K5: softmax over T, g_emb ----------------------------------
__global__ __launch_bounds__(128) void k_gemb(
    const float* __restrict__ z, const float* __restrict__ s_arr, float* __restrict__ g) {
  int blk = blockIdx.x;            // b*784 + k
  int b = blk / Kk, k = blk % Kk;
  int d = threadIdx.x;
  float sv[Tt];
  float mx = -3.4e38f;
#pragma unroll
  for (int t = 0; t < Tt; ++t) {
    sv[t] = s_arr[(t * Bb + b) * Kk + k];
    mx = fmaxf(mx, sv[t]);
  }
  float sum = 0.f;
#pragma unroll
  for (int t = 0; t < Tt; ++t) {
    sv[t] = expf(10.0f * (sv[t] - mx));
    sum += sv[t];
  }
  float isum = 1.0f / sum;
  float acc = 0.f;
#pragma unroll
  for (int t = 0; t < Tt; ++t)
    acc += sv[t] * isum * z[((size_t)(t * Bb + b) * Kk + k) * Dd + d];
  g[((size_t)b * Kk + k) * Dd + d] = acc;
}

// ---------------- K6: E = normalize(M @ g) via sparse bilinear structure -----
__global__ __launch_bounds__(64) void k_E(
    const float* __restrict__ Mmat, const float* __restrict__ g, float* __restrict__ E) {
  int row = blockIdx.x;            // b*N + n
  int b = row / Nn, n = row % Nn;
  int y = n / Ww, x = n % Ww;
  int x0 = x >> 1, y0 = y >> 1;
  int x1 = min(x0 + 1, 27), y1 = min(y0 + 1, 27);
  bool hx = (x1 != x0), hy = (y1 != y0);
  int k00 = y0 * 28 + x0, k01 = y0 * 28 + x1, k10 = y1 * 28 + x0, k11 = y1 * 28 + x1;
  const float* Mr = Mmat + (size_t)n * Kk;
  float m00 = Mr[k00];
  float m01 = hx ? Mr[k01] : 0.f;
  float m10 = hy ? Mr[k10] : 0.f;
  float m11 = (hx && hy) ? Mr[k11] : 0.f;
  const float* gb = g + (size_t)b * Kk * Dd;
  int lane = threadIdx.x;
  int l2 = lane + 64;
  float a0 = m00 * gb[k00 * Dd + lane] + m01 * gb[k01 * Dd + lane] +
             m10 * gb[k10 * Dd + lane] + m11 * gb[k11 * Dd + lane];
  float a1 = m00 * gb[k00 * Dd + l2] + m01 * gb[k01 * Dd + l2] +
             m10 * gb[k10 * Dd + l2] + m11 * gb[k11 * Dd + l2];
  float ss = a0 * a0 + a1 * a1;
  for (int off = 32; off; off >>= 1) ss += __shfl_xor(ss, off);
  float inv = 1.0f / fmaxf(sqrtf(ss), 1e-6f);
  E[(size_t)row * Dd + lane] = a0 * inv;
  E[(size_t)row * Dd + l2] = a1 * inv;
}

// ---------------- K7: Saff = (E E^T) * G, symmetric: lower-tri tiles + mirror
__global__ __launch_bounds__(256) void k_saff(
    const float* __restrict__ E, const float* __restrict__ P, float* __restrict__ S) {
  int blk = blockIdx.x;
  int b = blk / 1225;
  int rem = blk % 1225;
  int ti0 = (int)((sqrtf(8.f * rem + 1.f) - 1.f) * 0.5f);
  while ((ti0 + 1) * (ti0 + 2) / 2 <= rem) ++ti0;
  while (ti0 * (ti0 + 1) / 2 > rem) --ti0;
  int tj0 = rem - ti0 * (ti0 + 1) / 2;   // tj0 <= ti0
  int i0 = ti0 * 64, j0 = tj0 * 64;
  __shared__ __align__(16) float Ei_s[64 * 68];
  __shared__ __align__(16) float Ej_s[64 * 68];
  __shared__ float s_pxi[64], s_pyi[64], s_pxj[64], s_pyj[64];
  int tid = threadIdx.x;
  const float* Eb = E + (size_t)b * Nn * Dd;
  if (tid < 64) {
    s_pxi[tid] = P[(i0 + tid) * 2];
    s_pyi[tid] = P[(i0 + tid) * 2 + 1];
    s_pxj[tid] = P[(j0 + tid) * 2];
    s_pyj[tid] = P[(j0 + tid) * 2 + 1];
  }
  int ti = tid >> 4, tj = tid & 15;
  int ib = ti * 4, jb = tj * 4;
  float acc[4][4];
#pragma unroll
  for (int a = 0; a < 4; ++a)
#pragma unroll
    for (int c = 0; c < 4; ++c) acc[a][c] = 0.f;
  for (int kc = 0; kc < Dd; kc += 64) {
    __syncthreads();
    for (int idx = tid; idx < 64 * 64; idx += 256) {
      int ii = idx >> 6, dd = idx & 63;
      Ei_s[dd * 68 + ii] = Eb[(size_t)(i0 + ii) * Dd + kc + dd];
      Ej_s[dd * 68 + ii] = Eb[(size_t)(j0 + ii) * Dd + kc + dd];
    }
    __syncthreads();
#pragma unroll 8
    for (int kk = 0; kk < 64; ++kk) {
      const float4 a = *reinterpret_cast<const float4*>(&Ei_s[kk * 68 + ib]);
      const float4 q = *reinterpret_cast<const float4*>(&Ej_s[kk * 68 + jb]);
      acc[0][0] += a.x * q.x; acc[0][1] += a.x * q.y; acc[0][2] += a.x * q.z; acc[0][3] += a.x * q.w;
      acc[1][0] += a.y * q.x; acc[1][1] += a.y * q.y; acc[1][2] += a.y * q.z; acc[1][3] += a.y * q.w;
      acc[2][0] += a.z * q.x; acc[2][1] += a.z * q.y; acc[2][2] += a.z * q.z; acc[2][3] += a.z * q.w;
      acc[3][0] += a.w * q.x; acc[3][1] += a.w * q.y; acc[3][2] += a.w * q.z; acc[3][3] += a.w * q.w;
    }
  }
  float outv[4][4];
#pragma unroll
  for (int di = 0; di < 4; ++di) {
    float px = s_pxi[ib + di], py = s_pyi[ib + di];
#pragma unroll
    for (int dj = 0; dj < 4; ++dj) {
      float dx = px - s_pxj[jb + dj];
      float dy = py - s_pyj[jb + dj];
      float gg = 1.0f - expf(-(dx * dx + dy * dy) * (1.0f / 18.0f));
      outv[di][dj] = acc[di][dj] * gg;
    }
  }
  size_t ob = (size_t)b * Nn * Nn;
#pragma unroll
  for (int di = 0; di < 4; ++di) {
    float4 o = {outv[di][0], outv[di][1], outv[di][2], outv[di][3]};
    *reinterpret_cast<float4*>(&S[ob + (size_t)(i0 + ib + di) * Nn + j0 + jb]) = o;
  }
  if (i0 != j0) {
#pragma unroll
    for (int dj = 0; dj < 4; ++dj) {
      float4 o = {outv[0][dj], outv[1][dj], outv[2][dj], outv[3][dj]};
      *reinterpret_cast<float4*>(&S[ob + (size_t)(j0 + jb + dj) * Nn + i0 + ib]) = o;
    }
  }
}

// ---------------- K8: exact top-32 per row via 4-pass radix select -----------
__global__ __launch_bounds__(256) void k_topk(
    const float* __restrict__ S, float* __restrict__ topv, int* __restrict__ topi,
    float* __restrict__ dr, float* __restrict__ dc) {
  int row = blockIdx.x;
  int b = row / Nn;
  int tid = threadIdx.x;
  const float* Sr = S + (size_t)row * Nn;
  __shared__ unsigned hist[256 * 8];   // 8-way replicated to break atomic serialization
  __shared__ unsigned scan_s[256];
  __shared__ unsigned bcast[2];
  __shared__ unsigned sel_eq, sel_slot;
  __shared__ float drow_s;
  unsigned key[13];
#pragma unroll
  for (int j = 0; j < 13; ++j) {
    int c = tid + 256 * j;
    unsigned u = (c < Nn) ? __float_as_uint(Sr[c]) : 0xFF800000u;
    key[j] = u ^ (((unsigned)((int)u >> 31)) | 0x80000000u);  // monotone map
  }
  if (tid == 0) { sel_eq = 0; sel_slot = 0; drow_s = 0.f; }
  unsigned prefix = 0;
  unsigned k = NTOP;
  for (int pass = 0; pass < 4; ++pass) {
    int shift = 24 - 8 * pass;
#pragma unroll
    for (int i = 0; i < 8; ++i) hist[tid * 8 + i] = 0;
    __syncthreads();
    unsigned pmask = pass ? (0xFFFFFFFFu << (shift + 8)) : 0u;
#pragma unroll
    for (int j = 0; j < 13; ++j) {
      if ((key[j] & pmask) == prefix)
        atomicAdd(&hist[((key[j] >> shift) & 255u) * 8 + (tid & 7)], 1u);
    }
    __syncthreads();
    unsigned cnt = 0;
#pragma unroll
    for (int i = 0; i < 8; ++i) cnt += hist[tid * 8 + i];
    unsigned run = cnt;
    scan_s[tid] = run;
    for (int st = 1; st < 256; st <<= 1) {
      __syncthreads();
      unsigned add = (tid + st < 256) ? scan_s[tid + st] : 0u;
      __syncthreads();
      run += add;
      scan_s[tid] = run;
    }
    unsigned incl = run;
    unsigned excl = incl - cnt;
    if (excl < k && k <= incl) {
      bcast[0] = prefix | ((unsigned)tid << shift);
      bcast[1] = k - excl;
    }
    __syncthreads();
    prefix = bcast[0];
    k = bcast[1];
    __syncthreads();
  }
  unsigned T = prefix;   // exact key of 32nd-largest; k = #ties to take
  float esum = 0.f;
#pragma unroll
  for (int j = 0; j < 13; ++j) {
    int c = tid + 256 * j;
    if (c >= Nn) break;
    unsigned kj = key[j];
    bool take = kj > T;
    if (!take && kj == T) take = (atomicAdd(&sel_eq, 1u) < k);
    if (take) {
      unsigned slot = atomicAdd(&sel_slot, 1u);
      float v = __uint_as_float((kj & 0x80000000u) ? (kj ^ 0x80000000u) : ~kj);
      float e = __expf(10.f * v);
      topv[(size_t)row * NTOP + slot] = v;
      topi[(size_t)row * NTOP + slot] = c;
      atomicAdd(&dc[b * Nn + c], e - 1.f);
      esum += e;
    }
  }
  for (int off = 32; off; off >>= 1) esum += __shfl_xor(esum, off);
  if ((tid & 63) == 0) atomicAdd(&drow_s, esum);
  __syncthreads();
  if (tid == 0) dr[row] = (float)(Nn - NTOP) + drow_s;
}

__global__ void k_dcinit(float* __restrict__ dc) {
  int i = blockIdx.x * 256 + threadIdx.x;
  if (i < Bb * Nn) dc[i] = (float)Nn;
}

__global__ void k_inv(float* __restrict__ dr, float* __restrict__ dc) {
  int i = blockIdx.x * 256 + threadIdx.x;
  if (i < Bb * Nn) {
    dr[i] = 1.0f / dr[i];
    dc[i] = 1.0f / dc[i];
  }
}

// ---------------- K10: A0 row = invdr_i * invdc_j, then fix 32 entries -------
__global__ __launch_bounds__(256) void k_basefix(
    const float* __restrict__ invdr, const float* __restrict__ invdc,
    const float* __restrict__ topv, const int* __restrict__ topi,
    float* __restrict__ A0) {
  int row = blockIdx.x;            // b*N + i
  int b = row / Nn;
  float idr = invdr[row];
  const float4* dc4 = reinterpret_cast<const float4*>(invdc + b * Nn);
  float4* out4 = reinterpret_cast<float4*>(A0 + (size_t)row * Nn);
  for (int j = threadIdx.x; j < Nn / 4; j += 256) {
    float4 c = dc4[j];
    float4 o = {idr * c.x, idr * c.y, idr * c.z, idr * c.w};
    out4[j] = o;
  }
  __syncthreads();
  if (threadIdx.x < NTOP) {
    int gidx = row * NTOP + threadIdx.x;
    int col = topi[gidx];
    float e = __expf(10.f * topv[gidx]);
    A0[(size_t)row * Nn + col] = e * e * idr * invdc[b * Nn + col];
  }
}

extern "C" void kernel_launch(void* const* d_in, const int* in_sizes, int n_in,
                              void* d_out, int out_size, void* d_ws, size_t ws_size,
                              hipStream_t stream) {
  const float* fm     = (const float*)d_in[0];
  const float* Abank  = (const float*)d_in[1];
  const float* pw_w   = (const float*)d_in[2];
  const float* pw_b   = (const float*)d_in[3];
  const float* proj_w = (const float*)d_in[4];
  const float* proj_b = (const float*)d_in[5];
  const float* r      = (const float*)d_in[6];
  const float* Mmat   = (const float*)d_in[7];
  const float* P      = (const float*)d_in[8];
  float* out = (float*)d_out;
  float* E  = out;
  float* A0 = out + (size_t)Bb * Nn * Dd;

  float* ws = (float*)d_ws;
  float* rp    = ws;                       // 25,690,112 floats (dead after K2)
  float* z     = ws;                       //  6,422,528 floats (reuses rp region)
  float* pm    = ws + 25690112;            // 12,845,056
  float* wct   = ws + 38535168;            //     32,768
  float* bcv   = ws + 38567936;            //        128
  float* s_arr = ws + 38568064;            //     50,176
  float* g     = ws + 38618240;            //    401,408
  float* topv  = ws + 39019648;            //    401,408
  int*   topi  = (int*)(ws + 39421056);    //    401,408
  float* dr    = ws + 39822464;            //     12,544
  float* dc    = ws + 39835008;            //     12,544

  hipLaunchKernelGGL(k_warp_rowpool, dim3(Tt * Bb * Hh), dim3(256), 0, stream, fm, Abank, rp);
  hipLaunchKernelGGL(k_colpool, dim3(Tt * Bb * KX), dim3(256), 0, stream, rp, pm);
  hipLaunchKernelGGL(k_wc, dim3(Cc), dim3(128), 0, stream, pw_w, pw_b, proj_w, proj_b, wct, bcv);
  hipLaunchKernelGGL(k_zgemm, dim3(Tt * Bb * 28), dim3(256), 0, stream, pm, wct, bcv, z);
  hipLaunchKernelGGL(k_znorm, dim3(Tt * Bb * Kk / 4), dim3(256), 0, stream, z, r, s_arr);
  hipLaunchKernelGGL(k_gemb, dim3(Bb * Kk), dim3(128), 0, stream, z, s_arr, g);
  hipLaunchKernelGGL(k_E, dim3(Bb * Nn), dim3(64), 0, stream, Mmat, g, E);
  hipLaunchKernelGGL(k_saff, dim3(Bb * 1225), dim3(256), 0, stream, E, P, A0);
  hipLaunchKernelGGL(k_dcinit, dim3(49), dim3(256), 0, stream, dc);
  hipLaunchKernelGGL(k_topk, dim3(Bb * Nn), dim3(256), 0, stream, A0, topv, topi, dr, dc);
  hipLaunchKernelGGL(k_inv, dim3(49), dim3(256), 0, stream, dr, dc);
  hipLaunchKernelGGL(k_basefix, dim3(Bb * Nn), dim3(256), 0, stream, dr, dc, topv, topi, A0);
}

// Round 3
// 697.943 us; speedup vs baseline: 1.4359x; 1.1795x over previous
//
#include <hip/hip_runtime.h>
#include <hip/hip_bf16.h>

#define Hh 56
#define Ww 56
#define Cc 256
#define Tt 16
#define Bb 4
#define Nn 3136
#define Kk 784
#define KX 28
#define Dd 128
#define Mc 64
#define NTOP 32

// ---- K1: fused affine warp + bilinear + 9x9/s2 zero-pad avg-pool -> pm ------
// grid: b(4) x cgroup(64 of 4ch) x tgroup(4 of 4t) = 1024 blocks, 256 thr
__global__ __launch_bounds__(256) void k_fused_pool(
    const float* __restrict__ fm, const float* __restrict__ Abank, float* __restrict__ pm) {
  int idx = blockIdx.x;
  int b = idx & 3;
  int cg = (idx >> 2) & 63;
  int tg = idx >> 8;
  __shared__ float fm_s[4 * 3136];
  __shared__ float wsm[3136];
  __shared__ float rowp[1568];
  int tid = threadIdx.x;
  const float* fb = fm + ((size_t)b * Cc + cg * 4) * 3136;
  for (int e = tid; e < 4 * 3136; e += 256) fm_s[e] = fb[e];
  __syncthreads();
  for (int tt = 0; tt < 4; ++tt) {
    int t = tg * 4 + tt;
    const float* A = Abank + t * 6;
    float a00 = A[0], a01 = A[1], a02 = A[2], a10 = A[3], a11 = A[4], a12 = A[5];
    // per-thread coords for its ~13 pixels (t-dependent only)
    int off[13];
    float wxa[13], wya[13];
#pragma unroll
    for (int j = 0; j < 13; ++j) {
      int e = tid + 256 * j;
      if (e < 3136) {
        int h = e / 56, w = e - h * 56;
        float gx = (2.0f * w + 1.0f) / 56.0f - 1.0f;
        float gy = (2.0f * h + 1.0f) / 56.0f - 1.0f;
        float u = a00 * gx + a01 * gy + a02;
        float v = a10 * gx + a11 * gy + a12;
        float ix = ((u + 1.0f) * 56.0f - 1.0f) * 0.5f;
        float iy = ((v + 1.0f) * 56.0f - 1.0f) * 0.5f;
        float x0f = floorf(ix), y0f = floorf(iy);
        wxa[j] = ix - x0f;
        wya[j] = iy - y0f;
        int x0 = (int)x0f, y0 = (int)y0f;
        int x0c = min(max(x0, 0), 55), x1c = min(max(x0 + 1, 0), 55);
        int y0c = min(max(y0, 0), 55), y1c = min(max(y0 + 1, 0), 55);
        off[j] = (y0c * 56 + x0c) | ((x1c - x0c) << 12) | ((y1c - y0c) << 13);
      }
    }
    for (int c = 0; c < 4; ++c) {
      const float* fc = fm_s + c * 3136;
      // stage A: warped -> wsm
#pragma unroll
      for (int j = 0; j < 13; ++j) {
        int e = tid + 256 * j;
        if (e < 3136) {
          int pk = off[j];
          int base = pk & 4095;
          int dx = (pk >> 12) & 1;
          int dyy = (pk & (1 << 13)) ? 56 : 0;
          float v00 = fc[base], v01 = fc[base + dx];
          float v10 = fc[base + dyy], v11 = fc[base + dyy + dx];
          float wx = wxa[j], wy = wya[j];
          float top = v00 + wx * (v01 - v00);
          float bot = v10 + wx * (v11 - v10);
          wsm[e] = top + wy * (bot - top);
        }
      }
      __syncthreads();
      // stage B: row pool (horizontal 9, stride 2) -> rowp[56][28]
      for (int e = tid; e < 1568; e += 256) {
        int h = e / 28, kx = e - h * 28;
        int xs = 2 * kx - 4;
        int lo = max(xs, 0), hi = min(xs + 8, 55);
        float s = 0.f;
        const float* wr = wsm + h * 56;
        for (int x = lo; x <= hi; ++x) s += wr[x];
        rowp[e] = s;
      }
      __syncthreads();
      // stage C: col pool (vertical 9, stride 2) -> pm
      float* po = pm + ((size_t)(t * Bb + b) * Cc + cg * 4 + c) * Kk;
      for (int e = tid; e < 784; e += 256) {
        int ky = e / 28, kx = e - ky * 28;
        int ys = 2 * ky - 4;
        int lo = max(ys, 0), hi = min(ys + 8, 55);
        float s = 0.f;
        for (int h = lo; h <= hi; ++h) s += rowp[h * 28 + kx];
        po[e] = s * (1.0f / 81.0f);
      }
      __syncthreads();
    }
  }
}

// ---------------- K3a: combined weight Wc^T [c][d] and bias bc ---------------
__global__ __launch_bounds__(128) void k_wc(
    const float* __restrict__ pw_w, const float* __restrict__ pw_b,
    const float* __restrict__ proj_w, const float* __restrict__ proj_b,
    float* __restrict__ wct, float* __restrict__ bc) {
  int c = blockIdx.x;
  int d = threadIdx.x;
  float acc = 0.f;
  for (int m = 0; m < Mc; ++m) acc += proj_w[d * Mc + m] * pw_w[m * Cc + c];
  wct[c * Dd + d] = acc;
  if (c == 0) {
    float bb = proj_b[d];
    for (int m = 0; m < Mc; ++m) bb += proj_w[d * Mc + m] * pw_b[m];
    bc[d] = bb;
  }
}

// ---------------- K3b: z[tb,k,d] = sum_c pm[tb,c,k]*wct[c,d] + bc[d] ---------
__global__ __launch_bounds__(256) void k_zgemm(
    const float* __restrict__ pm, const float* __restrict__ wct,
    const float* __restrict__ bc, float* __restrict__ z) {
  int blk = blockIdx.x;            // tb*28 + ktile
  int tb = blk / 28;
  int k0 = (blk % 28) * 28;
  int tid = threadIdx.x;
  int d = tid & 127;
  int kg = tid >> 7;               // 0..1
  __shared__ float pm_s[64 * 28];
  __shared__ float wc_s[64 * Dd];
  float acc[14];
#pragma unroll
  for (int j = 0; j < 14; ++j) acc[j] = 0.f;
  float bcd = bc[d];
  const float* pmb = pm + (size_t)tb * Cc * Kk;
  for (int c0 = 0; c0 < Cc; c0 += 64) {
    for (int idx = tid; idx < 64 * 28; idx += 256) {
      int c = idx / 28, kx = idx - c * 28;
      pm_s[idx] = pmb[(size_t)(c0 + c) * Kk + k0 + kx];
    }
    for (int idx = tid; idx < 64 * Dd; idx += 256) wc_s[idx] = wct[c0 * Dd + idx];
    __syncthreads();
    for (int c = 0; c < 64; ++c) {
      float w = wc_s[c * Dd + d];
#pragma unroll
      for (int j = 0; j < 14; ++j) acc[j] += pm_s[c * 28 + kg * 14 + j] * w;
    }
    __syncthreads();
  }
#pragma unroll
  for (int j = 0; j < 14; ++j) {
    int k = k0 + kg * 14 + j;
    z[((size_t)tb * Kk + k) * Dd + d] = acc[j] + bcd;
  }
}

// ---------------- K4: normalize z rows, s = zn . r ---------------------------
__global__ __launch_bounds__(256) void k_znorm(
    float* __restrict__ z, const float* __restrict__ r, float* __restrict__ s_arr) {
  int row = blockIdx.x * 4 + (threadIdx.x >> 6);
  int lane = threadIdx.x & 63;
  float* zr = z + (size_t)row * Dd;
  float z0 = zr[lane], z1 = zr[lane + 64];
  float ss = z0 * z0 + z1 * z1;
  for (int off = 32; off; off >>= 1) ss += __shfl_xor(ss, off);
  float inv = 1.0f / fmaxf(sqrtf(ss), 1e-6f);
  z0 *= inv; z1 *= inv;
  zr[lane] = z0; zr[lane + 64] = z1;
  float sd = z0 * r[lane] + z1 * r[lane + 64];
  for (int off = 32; off; off >>= 1) sd += __shfl_xor(sd, off);
  if (lane == 0) s_arr[row] = sd;
}

// ---------------- K5: softmax over T, g_emb ----------------------------------
__global__ __launch_bounds__(128) void k_gemb(
    const float* __restrict__ z, const float* __restrict__ s_arr, float* __restrict__ g) {
  int blk = blockIdx.x;            // b*784 + k
  int b = blk / Kk, k = blk % Kk;
  int d = threadIdx.x;
  float sv[Tt];
  float mx = -3.4e38f;
#pragma unroll
  for (int t = 0; t < Tt; ++t) {
    sv[t] = s_arr[(t * Bb + b) * Kk + k];
    mx = fmaxf(mx, sv[t]);
  }
  float sum = 0.f;
#pragma unroll
  for (int t = 0; t < Tt; ++t) {
    sv[t] = expf(10.0f * (sv[t] - mx));
    sum += sv[t];
  }
  float isum = 1.0f / sum;
  float acc = 0.f;
#pragma unroll
  for (int t = 0; t < Tt; ++t)
    acc += sv[t] * isum * z[((size_t)(t * Bb + b) * Kk + k) * Dd + d];
  g[((size_t)b * Kk + k) * Dd + d] = acc;
}

// ---------------- K6: E = normalize(M @ g) via sparse bilinear structure -----
__global__ __launch_bounds__(64) void k_E(
    const float* __restrict__ Mmat, const float* __restrict__ g, float* __restrict__ E) {
  int row = blockIdx.x;            // b*N + n
  int b = row / Nn, n = row % Nn;
  int y = n / Ww, x = n % Ww;
  int x0 = x >> 1, y0 = y >> 1;
  int x1 = min(x0 + 1, 27), y1 = min(y0 + 1, 27);
  bool hx = (x1 != x0), hy = (y1 != y0);
  int k00 = y0 * 28 + x0, k01 = y0 * 28 + x1, k10 = y1 * 28 + x0, k11 = y1 * 28 + x1;
  const float* Mr = Mmat + (size_t)n * Kk;
  float m00 = Mr[k00];
  float m01 = hx ? Mr[k01] : 0.f;
  float m10 = hy ? Mr[k10] : 0.f;
  float m11 = (hx && hy) ? Mr[k11] : 0.f;
  const float* gb = g + (size_t)b * Kk * Dd;
  int lane = threadIdx.x;
  int l2 = lane + 64;
  float a0 = m00 * gb[k00 * Dd + lane] + m01 * gb[k01 * Dd + lane] +
             m10 * gb[k10 * Dd + lane] + m11 * gb[k11 * Dd + lane];
  float a1 = m00 * gb[k00 * Dd + l2] + m01 * gb[k01 * Dd + l2] +
             m10 * gb[k10 * Dd + l2] + m11 * gb[k11 * Dd + l2];
  float ss = a0 * a0 + a1 * a1;
  for (int off = 32; off; off >>= 1) ss += __shfl_xor(ss, off);
  float inv = 1.0f / fmaxf(sqrtf(ss), 1e-6f);
  E[(size_t)row * Dd + lane] = a0 * inv;
  E[(size_t)row * Dd + l2] = a1 * inv;
}

// ---------------- K7: Saff = (E E^T) * G, symmetric: lower-tri tiles + mirror
__global__ __launch_bounds__(256) void k_saff(
    const float* __restrict__ E, const float* __restrict__ P, float* __restrict__ S) {
  int blk = blockIdx.x;
  int b = blk / 1225;
  int rem = blk % 1225;
  int ti0 = (int)((sqrtf(8.f * rem + 1.f) - 1.f) * 0.5f);
  while ((ti0 + 1) * (ti0 + 2) / 2 <= rem) ++ti0;
  while (ti0 * (ti0 + 1) / 2 > rem) --ti0;
  int tj0 = rem - ti0 * (ti0 + 1) / 2;   // tj0 <= ti0
  int i0 = ti0 * 64, j0 = tj0 * 64;
  __shared__ __align__(16) float Ei_s[64 * 68];
  __shared__ __align__(16) float Ej_s[64 * 68];
  __shared__ float s_pxi[64], s_pyi[64], s_pxj[64], s_pyj[64];
  int tid = threadIdx.x;
  const float* Eb = E + (size_t)b * Nn * Dd;
  if (tid < 64) {
    s_pxi[tid] = P[(i0 + tid) * 2];
    s_pyi[tid] = P[(i0 + tid) * 2 + 1];
    s_pxj[tid] = P[(j0 + tid) * 2];
    s_pyj[tid] = P[(j0 + tid) * 2 + 1];
  }
  int ti = tid >> 4, tj = tid & 15;
  int ib = ti * 4, jb = tj * 4;
  float acc[4][4];
#pragma unroll
  for (int a = 0; a < 4; ++a)
#pragma unroll
    for (int c = 0; c < 4; ++c) acc[a][c] = 0.f;
  for (int kc = 0; kc < Dd; kc += 64) {
    __syncthreads();
    for (int idx = tid; idx < 64 * 64; idx += 256) {
      int ii = idx >> 6, dd = idx & 63;
      Ei_s[dd * 68 + ii] = Eb[(size_t)(i0 + ii) * Dd + kc + dd];
      Ej_s[dd * 68 + ii] = Eb[(size_t)(j0 + ii) * Dd + kc + dd];
    }
    __syncthreads();
#pragma unroll 8
    for (int kk = 0; kk < 64; ++kk) {
      const float4 a = *reinterpret_cast<const float4*>(&Ei_s[kk * 68 + ib]);
      const float4 q = *reinterpret_cast<const float4*>(&Ej_s[kk * 68 + jb]);
      acc[0][0] += a.x * q.x; acc[0][1] += a.x * q.y; acc[0][2] += a.x * q.z; acc[0][3] += a.x * q.w;
      acc[1][0] += a.y * q.x; acc[1][1] += a.y * q.y; acc[1][2] += a.y * q.z; acc[1][3] += a.y * q.w;
      acc[2][0] += a.z * q.x; acc[2][1] += a.z * q.y; acc[2][2] += a.z * q.z; acc[2][3] += a.z * q.w;
      acc[3][0] += a.w * q.x; acc[3][1] += a.w * q.y; acc[3][2] += a.w * q.z; acc[3][3] += a.w * q.w;
    }
  }
  float outv[4][4];
#pragma unroll
  for (int di = 0; di < 4; ++di) {
    float px = s_pxi[ib + di], py = s_pyi[ib + di];
#pragma unroll
    for (int dj = 0; dj < 4; ++dj) {
      float dx = px - s_pxj[jb + dj];
      float dy = py - s_pyj[jb + dj];
      float gg = 1.0f - expf(-(dx * dx + dy * dy) * (1.0f / 18.0f));
      outv[di][dj] = acc[di][dj] * gg;
    }
  }
  size_t ob = (size_t)b * Nn * Nn;
#pragma unroll
  for (int di = 0; di < 4; ++di) {
    float4 o = {outv[di][0], outv[di][1], outv[di][2], outv[di][3]};
    *reinterpret_cast<float4*>(&S[ob + (size_t)(i0 + ib + di) * Nn + j0 + jb]) = o;
  }
  if (i0 != j0) {
#pragma unroll
    for (int dj = 0; dj < 4; ++dj) {
      float4 o = {outv[0][dj], outv[1][dj], outv[2][dj], outv[3][dj]};
      *reinterpret_cast<float4*>(&S[ob + (size_t)(j0 + jb + dj) * Nn + i0 + ib]) = o;
    }
  }
}

// ---------------- K8: exact top-32 per row via 4-pass radix select -----------
__global__ __launch_bounds__(256) void k_topk(
    const float* __restrict__ S, float* __restrict__ topv, int* __restrict__ topi,
    float* __restrict__ dr, float* __restrict__ dc) {
  int row = blockIdx.x;
  int b = row / Nn;
  int tid = threadIdx.x;
  const float* Sr = S + (size_t)row * Nn;
  __shared__ unsigned hist[256 * 8];
  __shared__ unsigned scan_s[256];
  __shared__ unsigned bcast[2];
  __shared__ unsigned sel_eq, sel_slot;
  __shared__ float drow_s;
  unsigned key[13];
#pragma unroll
  for (int j = 0; j < 13; ++j) {
    int c = tid + 256 * j;
    unsigned u = (c < Nn) ? __float_as_uint(Sr[c]) : 0xFF800000u;
    key[j] = u ^ (((unsigned)((int)u >> 31)) | 0x80000000u);
  }
  if (tid == 0) { sel_eq = 0; sel_slot = 0; drow_s = 0.f; }
  unsigned prefix = 0;
  unsigned k = NTOP;
  for (int pass = 0; pass < 4; ++pass) {
    int shift = 24 - 8 * pass;
#pragma unroll
    for (int i = 0; i < 8; ++i) hist[tid * 8 + i] = 0;
    __syncthreads();
    unsigned pmask = pass ? (0xFFFFFFFFu << (shift + 8)) : 0u;
#pragma unroll
    for (int j = 0; j < 13; ++j) {
      if ((key[j] & pmask) == prefix)
        atomicAdd(&hist[((key[j] >> shift) & 255u) * 8 + (tid & 7)], 1u);
    }
    __syncthreads();
    unsigned cnt = 0;
#pragma unroll
    for (int i = 0; i < 8; ++i) cnt += hist[tid * 8 + i];
    unsigned run = cnt;
    scan_s[tid] = run;
    for (int st = 1; st < 256; st <<= 1) {
      __syncthreads();
      unsigned add = (tid + st < 256) ? scan_s[tid + st] : 0u;
      __syncthreads();
      run += add;
      scan_s[tid] = run;
    }
    unsigned incl = run;
    unsigned excl = incl - cnt;
    if (excl < k && k <= incl) {
      bcast[0] = prefix | ((unsigned)tid << shift);
      bcast[1] = k - excl;
    }
    __syncthreads();
    prefix = bcast[0];
    k = bcast[1];
    __syncthreads();
  }
  unsigned T = prefix;
  float esum = 0.f;
#pragma unroll
  for (int j = 0; j < 13; ++j) {
    int c = tid + 256 * j;
    if (c >= Nn) break;
    unsigned kj = key[j];
    bool take = kj > T;
    if (!take && kj == T) take = (atomicAdd(&sel_eq, 1u) < k);
    if (take) {
      unsigned slot = atomicAdd(&sel_slot, 1u);
      float v = __uint_as_float((kj & 0x80000000u) ? (kj ^ 0x80000000u) : ~kj);
      float e = __expf(10.f * v);
      topv[(size_t)row * NTOP + slot] = v;
      topi[(size_t)row * NTOP + slot] = c;
      atomicAdd(&dc[b * Nn + c], e - 1.f);
      esum += e;
    }
  }
  for (int off = 32; off; off >>= 1) esum += __shfl_xor(esum, off);
  if ((tid & 63) == 0) atomicAdd(&drow_s, esum);
  __syncthreads();
  if (tid == 0) dr[row] = (float)(Nn - NTOP) + drow_s;
}

__global__ void k_dcinit(float* __restrict__ dc) {
  int i = blockIdx.x * 256 + threadIdx.x;
  if (i < Bb * Nn) dc[i] = (float)Nn;
}

__global__ void k_inv(float* __restrict__ dr, float* __restrict__ dc) {
  int i = blockIdx.x * 256 + threadIdx.x;
  if (i < Bb * Nn) {
    dr[i] = 1.0f / dr[i];
    dc[i] = 1.0f / dc[i];
  }
}

// ---------------- K10: A0 row = invdr_i * invdc_j, then fix 32 entries -------
__global__ __launch_bounds__(256) void k_basefix(
    const float* __restrict__ invdr, const float* __restrict__ invdc,
    const float* __restrict__ topv, const int* __restrict__ topi,
    float* __restrict__ A0) {
  int row = blockIdx.x;            // b*N + i
  int b = row / Nn;
  float idr = invdr[row];
  const float4* dc4 = reinterpret_cast<const float4*>(invdc + b * Nn);
  float4* out4 = reinterpret_cast<float4*>(A0 + (size_t)row * Nn);
  for (int j = threadIdx.x; j < Nn / 4; j += 256) {
    float4 c = dc4[j];
    float4 o = {idr * c.x, idr * c.y, idr * c.z, idr * c.w};
    out4[j] = o;
  }
  __syncthreads();
  if (threadIdx.x < NTOP) {
    int gidx = row * NTOP + threadIdx.x;
    int col = topi[gidx];
    float e = __expf(10.f * topv[gidx]);
    A0[(size_t)row * Nn + col] = e * e * idr * invdc[b * Nn + col];
  }
}

extern "C" void kernel_launch(void* const* d_in, const int* in_sizes, int n_in,
                              void* d_out, int out_size, void* d_ws, size_t ws_size,
                              hipStream_t stream) {
  const float* fm     = (const float*)d_in[0];
  const float* Abank  = (const float*)d_in[1];
  const float* pw_w   = (const float*)d_in[2];
  const float* pw_b   = (const float*)d_in[3];
  const float* proj_w = (const float*)d_in[4];
  const float* proj_b = (const float*)d_in[5];
  const float* r      = (const float*)d_in[6];
  const float* Mmat   = (const float*)d_in[7];
  const float* P      = (const float*)d_in[8];
  float* out = (float*)d_out;
  float* E  = out;
  float* A0 = out + (size_t)Bb * Nn * Dd;

  float* ws = (float*)d_ws;
  float* pm    = ws;                       // 12,845,056 floats
  float* z     = ws + 12845056;            //  6,422,528
  float* wct   = ws + 19267584;            //     32,768
  float* bcv   = ws + 19300352;            //        128
  float* s_arr = ws + 19300480;            //     50,176
  float* g     = ws + 19350656;            //    401,408
  float* topv  = ws + 19752064;            //    401,408
  int*   topi  = (int*)(ws + 20153472);    //    401,408
  float* dr    = ws + 20554880;            //     12,544
  float* dc    = ws + 20567424;            //     12,544

  hipLaunchKernelGGL(k_fused_pool, dim3(1024), dim3(256), 0, stream, fm, Abank, pm);
  hipLaunchKernelGGL(k_wc, dim3(Cc), dim3(128), 0, stream, pw_w, pw_b, proj_w, proj_b, wct, bcv);
  hipLaunchKernelGGL(k_zgemm, dim3(Tt * Bb * 28), dim3(256), 0, stream, pm, wct, bcv, z);
  hipLaunchKernelGGL(k_znorm, dim3(Tt * Bb * Kk / 4), dim3(256), 0, stream, z, r, s_arr);
  hipLaunchKernelGGL(k_gemb, dim3(Bb * Kk), dim3(128), 0, stream, z, s_arr, g);
  hipLaunchKernelGGL(k_E, dim3(Bb * Nn), dim3(64), 0, stream, Mmat, g, E);
  hipLaunchKernelGGL(k_saff, dim3(Bb * 1225), dim3(256), 0, stream, E, P, A0);
  hipLaunchKernelGGL(k_dcinit, dim3(49), dim3(256), 0, stream, dc);
  hipLaunchKernelGGL(k_topk, dim3(Bb * Nn), dim3(256), 0, stream, A0, topv, topi, dr, dc);
  hipLaunchKernelGGL(k_inv, dim3(49), dim3(256), 0, stream, dr, dc);
  hipLaunchKernelGGL(k_basefix, dim3(Bb * Nn), dim3(256), 0, stream, dr, dc, topv, topi, A0);
}